// Round 3
// baseline (526.749 us; speedup 1.0000x reference)
//
#include <hip/hip_runtime.h>

#define CH 32      // chunk length
#define DD 64      // dk = dv
#define NCHUNK 256 // chunks per (b,h)
#define SEQ 8192   // sequence length
#define BH 32      // b*h
#define NSEG 16    // segments for the two-level scan
#define CPS 16     // chunks per segment (NCHUNK / NSEG)
#define SEGMASK 511 // BH*NSEG - 1
#define SEGSHIFT 9  // log2(BH*NSEG)

typedef _Float16 half8 __attribute__((ext_vector_type(8)));
typedef float f32x4 __attribute__((ext_vector_type(4)));
typedef unsigned short u16;

#define MFMA16(a, b, c) __builtin_amdgcn_mfma_f32_16x16x32_f16((a), (b), (c), 0, 0, 0)

// split fp32 -> f16 hi + f16 lo (hi+lo reconstructs to ~2^-21 rel), store frag
__device__ __forceinline__ void split_store(const float* src8, bool neg, u16* dst) {
    half8 hi, lo;
#pragma unroll
    for (int j = 0; j < 8; ++j) {
        float x = neg ? -src8[j] : src8[j];
        _Float16 xh = (_Float16)x;
        hi[j] = xh;
        lo[j] = (_Float16)(x - (float)xh);
    }
    *(half8*)dst = hi;
    *(half8*)(dst + 8) = lo;
}

__device__ __forceinline__ void hi_store(const float* src8, u16* dst) {
    half8 hi;
#pragma unroll
    for (int j = 0; j < 8; ++j) hi[j] = (_Float16)src8[j];
    *(half8*)dst = hi;
}

__device__ __forceinline__ void split8(const float* src8, half8* hi, half8* lo) {
#pragma unroll
    for (int j = 0; j < 8; ++j) {
        float x = src8[j];
        _Float16 xh = (_Float16)x;
        (*hi)[j] = xh;
        (*lo)[j] = (_Float16)(x - (float)xh);
    }
}

// ---------------------------------------------------------------------------
// Kernel 1: per-chunk preprocessing. One block (256 thr = 4 waves) per chunk.
// Unchanged from the 575us version.
// ---------------------------------------------------------------------------
__global__ __launch_bounds__(256) void prep_kernel(
    float* __restrict__ q, float* __restrict__ k,
    const float* __restrict__ v, const float* __restrict__ beta,
    float* __restrict__ u_out, u16* __restrict__ qfrag, u16* __restrict__ pfrag)
{
    const int blk = blockIdx.x;
    const int bh = blk >> 8;
    const int cc = blk & 255;
    const size_t base = ((size_t)bh * SEQ + (size_t)cc * CH) * DD;
    const int t = threadIdx.x;

    __shared__ __align__(16) float qs[CH][68];
    __shared__ __align__(16) float ks[CH][68];
    __shared__ __align__(16) float kb[CH][68];
    __shared__ __align__(16) float vb[CH][68];
    __shared__ __align__(16) float wl[CH][68];
    __shared__ float A[CH][33];
    __shared__ __align__(16) float Pl[CH][36];
    __shared__ float bet[CH];
    __shared__ float rnq[CH];
    __shared__ float rnk[CH];

    if (t < CH) bet[t] = beta[(size_t)bh * SEQ + (size_t)cc * CH + t];
    for (int rep = 0; rep < 2; ++rep) {
        int idx = t + rep * 256;          // float4 index (512 total per array)
        int r = idx >> 4, d4 = idx & 15;
        float4 vq = *(const float4*)&q[base + (size_t)idx * 4];
        float4 vk = *(const float4*)&k[base + (size_t)idx * 4];
        float4 vv = *(const float4*)&v[base + (size_t)idx * 4];
        *(float4*)&qs[r][4 * d4] = vq;
        *(float4*)&ks[r][4 * d4] = vk;
        *(float4*)&vb[r][4 * d4] = vv;
    }
    __syncthreads();
    if (t < CH) {
        float ss = 0.f;
        for (int d4 = 0; d4 < 16; ++d4) {
            float4 x = *(const float4*)&qs[t][4 * d4];
            ss += x.x * x.x + x.y * x.y + x.z * x.z + x.w * x.w;
        }
        rnq[t] = rsqrtf(ss + 1e-6f);
    } else if (t < 2 * CH) {
        int r = t - CH;
        float ss = 0.f;
        for (int d4 = 0; d4 < 16; ++d4) {
            float4 x = *(const float4*)&ks[r][4 * d4];
            ss += x.x * x.x + x.y * x.y + x.z * x.z + x.w * x.w;
        }
        rnk[r] = rsqrtf(ss + 1e-6f);
    }
    __syncthreads();
    for (int rep = 0; rep < 2; ++rep) {
        int idx = t + rep * 256;
        int r = idx >> 4, d4 = idx & 15;
        float4 vq = *(const float4*)&qs[r][4 * d4];
        float4 vk = *(const float4*)&ks[r][4 * d4];
        float4 vv = *(const float4*)&vb[r][4 * d4];
        float fq = rnq[r], fk = rnk[r], fb = bet[r];
        vq.x *= fq; vq.y *= fq; vq.z *= fq; vq.w *= fq;
        vk.x *= fk; vk.y *= fk; vk.z *= fk; vk.w *= fk;
        float4 vkb = make_float4(vk.x * fb, vk.y * fb, vk.z * fb, vk.w * fb);
        float4 vvb = make_float4(vv.x * fb, vv.y * fb, vv.z * fb, vv.w * fb);
        *(float4*)&qs[r][4 * d4] = vq;
        *(float4*)&ks[r][4 * d4] = vk;
        *(float4*)&kb[r][4 * d4] = vkb;
        *(float4*)&vb[r][4 * d4] = vvb;
    }
    __syncthreads();
    // ---- A/P via MFMA f16 hi/lo ----
    {
        const int l = t & 63, n = l & 15, h = l >> 4;
        const int wv = t >> 6, mt = wv >> 1, nt = wv & 1;
        half8 kbhi[2], kblo[2], qhi[2], qlo[2], khi[2], klo[2];
#pragma unroll
        for (int kt = 0; kt < 2; ++kt) {
            float a8[8], q8[8], b8[8];
#pragma unroll
            for (int jj = 0; jj < 8; ++jj) {
                a8[jj] = kb[16 * mt + n][32 * kt + 8 * h + jj];
                q8[jj] = qs[16 * mt + n][32 * kt + 8 * h + jj];
                b8[jj] = ks[16 * nt + n][32 * kt + 8 * h + jj];
            }
            split8(a8, &kbhi[kt], &kblo[kt]);
            split8(q8, &qhi[kt], &qlo[kt]);
            split8(b8, &khi[kt], &klo[kt]);
        }
        f32x4 gacc = {0.f, 0.f, 0.f, 0.f};
        f32x4 pacc = {0.f, 0.f, 0.f, 0.f};
#pragma unroll
        for (int kt = 0; kt < 2; ++kt) {
            gacc = MFMA16(kbhi[kt], khi[kt], gacc);
            gacc = MFMA16(kbhi[kt], klo[kt], gacc);
            gacc = MFMA16(kblo[kt], khi[kt], gacc);
            pacc = MFMA16(qhi[kt], khi[kt], pacc);
            pacc = MFMA16(qhi[kt], klo[kt], pacc);
            pacc = MFMA16(qlo[kt], khi[kt], pacc);
        }
#pragma unroll
        for (int i = 0; i < 4; ++i) {
            int ig = 16 * mt + 4 * h + i, jg = 16 * nt + n;
            A[ig][jg] = (jg < ig) ? -gacc[i] : 0.f;
            Pl[ig][jg] = (jg <= ig) ? pacc[i] : 0.f;
        }
    }
    __syncthreads();
    // forward substitution, single wave, columns in registers, no barriers.
    if (t < 64) {
        const int col = t & 31;
        float creg[CH];
        #pragma unroll
        for (int j = 0; j < CH; ++j) creg[j] = A[j][col];
        #pragma unroll
        for (int i = 1; i < CH; ++i) {
            float s = 0.f;
            #pragma unroll
            for (int j = 1; j < i; ++j) s += A[i][j] * creg[j];
            if (col < i) creg[i] += s;
        }
        if (t < 32) {
            #pragma unroll
            for (int j = 0; j < CH; ++j) A[j][col] = creg[j];
        }
    }
    __syncthreads();
    // u = (A+I)@vb -> global row-major (o-region) ; w = (A+I)@kb -> wl (LDS)
    if (t < 128) {
        const int d4 = t & 15;
        const int i0 = (t >> 4) * 4;
        float4 su[4], sw[4];
        #pragma unroll
        for (int ii = 0; ii < 4; ++ii) {
            su[ii] = *(const float4*)&vb[i0 + ii][4 * d4];
            sw[ii] = *(const float4*)&kb[i0 + ii][4 * d4];
        }
        for (int j = 0; j <= i0 + 2; ++j) {
            float4 vv = *(const float4*)&vb[j][4 * d4];
            float4 vk = *(const float4*)&kb[j][4 * d4];
            #pragma unroll
            for (int ii = 0; ii < 4; ++ii) {
                float a = (j < i0 + ii) ? A[i0 + ii][j] : 0.f;
                su[ii].x += a * vv.x; su[ii].y += a * vv.y;
                su[ii].z += a * vv.z; su[ii].w += a * vv.w;
                sw[ii].x += a * vk.x; sw[ii].y += a * vk.y;
                sw[ii].z += a * vk.z; sw[ii].w += a * vk.w;
            }
        }
        #pragma unroll
        for (int ii = 0; ii < 4; ++ii) {
            *(float4*)&u_out[base + (size_t)(i0 + ii) * DD + 4 * d4] = su[ii];
            *(float4*)&wl[i0 + ii][4 * d4] = sw[ii];
        }
    }
    __syncthreads();
    // ---- pack phase: f16 frag stores ----
    {
        const int l = t & 63;
        const int n = l & 15, h = l >> 4;
        const int tw = t >> 6;           // 0..3
        const int mt = tw >> 1, kt = tw & 1;
        const size_t cslot = (size_t)bh * 256 + cc;
        // -w hi/lo A-frags -> over q
        {
            float tmp[8];
            #pragma unroll
            for (int j = 0; j < 8; ++j) tmp[j] = wl[mt * 16 + n][kt * 32 + h * 8 + j];
            split_store(tmp, true, (u16*)q + cslot * 4096 + (size_t)tw * 1024 + l * 16);
        }
        // k^T hi/lo A-frags -> over k
        {
            float tmp[8];
            #pragma unroll
            for (int j = 0; j < 8; ++j) tmp[j] = ks[h * 8 + j][tw * 16 + n];
            split_store(tmp, false, (u16*)k + cslot * 4096 + (size_t)tw * 1024 + l * 16);
        }
        // q hi A-frags -> ws
        {
            float tmp[8];
            #pragma unroll
            for (int j = 0; j < 8; ++j) tmp[j] = qs[mt * 16 + n][kt * 32 + h * 8 + j];
            hi_store(tmp, qfrag + cslot * 2048 + (size_t)tw * 512 + l * 8);
        }
        // P hi A-frags -> ws (2 tiles)
        if (t < 128) {
            float tmp[8];
            #pragma unroll
            for (int j = 0; j < 8; ++j) tmp[j] = Pl[tw * 16 + n][h * 8 + j];
            hi_store(tmp, pfrag + cslot * 1024 + (size_t)tw * 512 + l * 8);
        }
    }
}

// ---------------------------------------------------------------------------
// Pass 1: per-segment transfer function. Recurrence per chunk is affine:
//   S' = M S + b,  M = I - kT w,  b = kT u0.
// For each (bh, seg) compute T_seg = prod M_c (init I, u0 = 0) and
// B_seg (init 0, real u0). Grid: 8 r-slots x 512 (bh*16+seg); r = g*2+tb.
// Blocks sharing (bh,seg) are 512 apart -> same XCD L2 for shared w/kT reads.
// Chain length 16 (was 32); 4096 waves (was 2048).
// ---------------------------------------------------------------------------
__global__ __launch_bounds__(64) void seg_tf_kernel(
    const u16* __restrict__ wfrag, const u16* __restrict__ ktfrag,
    const float* __restrict__ uo, float* __restrict__ Tbuf, float* __restrict__ Bbuf)
{
    const int idx = blockIdx.x;
    const int bhseg = idx & SEGMASK;  // bh*NSEG + seg
    const int r = idx >> SEGSHIFT;    // 0..7
    const int g = r >> 1;             // column group (16 cols of state)
    const int tb = r & 1;             // 0 = T (identity init), 1 = B (u0 path)
    const int bh = bhseg >> 4, seg = bhseg & (NSEG - 1);
    const int l = threadIdx.x;
    const int n = l & 15, h = l >> 4;
    const int c0 = seg * CPS, c1 = c0 + CPS;

    __shared__ __align__(16) float Sc[16 * 76];
    __shared__ __align__(16) float uc[16 * 44];

    const u16* wb = wfrag + (size_t)bh * 256 * 4096;
    const u16* kb = ktfrag + (size_t)bh * 256 * 4096;
    const float* ub = uo + (size_t)bh * SEQ * DD + (size_t)g * 16;

    f32x4 Sacc[4];
    const f32x4 fzero = {0.f, 0.f, 0.f, 0.f};
#pragma unroll
    for (int mt = 0; mt < 4; ++mt) Sacc[mt] = fzero;
    if (!tb) {  // T starts as identity slice: row == global col (g*16+n)
#pragma unroll
        for (int mt = 0; mt < 4; ++mt)
#pragma unroll
            for (int i = 0; i < 4; ++i)
                if (16 * mt + 4 * h + i == g * 16 + n) Sacc[mt][i] = 1.f;
    }

    // prefetch chunk c0: w frags (+ u0 for B path)
    half8 wcur[8];
    float u0cur[8];
#pragma unroll
    for (int z = 0; z < 8; ++z) u0cur[z] = 0.f;
    {
        const u16* wc = wb + (size_t)c0 * 4096;
#pragma unroll
        for (int tw = 0; tw < 4; ++tw) {
            wcur[tw * 2 + 0] = *(const half8*)(wc + (size_t)tw * 1024 + l * 16);
            wcur[tw * 2 + 1] = *(const half8*)(wc + (size_t)tw * 1024 + l * 16 + 8);
        }
        if (tb) {
#pragma unroll
            for (int mt = 0; mt < 2; ++mt)
#pragma unroll
                for (int i = 0; i < 4; ++i)
                    u0cur[mt * 4 + i] = ub[(size_t)(c0 * 32 + mt * 16 + h * 4 + i) * 64 + n];
        }
    }

    for (int c = c0; c < c1; ++c) {
#pragma unroll
        for (int mt = 0; mt < 4; ++mt)
            *(f32x4*)&Sc[n * 76 + mt * 16 + h * 4] = Sacc[mt];

        const u16* kc = kb + (size_t)c * 4096;
        half8 kT[8];
#pragma unroll
        for (int mt = 0; mt < 4; ++mt) {
            kT[mt * 2 + 0] = *(const half8*)(kc + (size_t)mt * 1024 + l * 16);
            kT[mt * 2 + 1] = *(const half8*)(kc + (size_t)mt * 1024 + l * 16 + 8);
        }

        const int cn = (c + 1 < c1) ? c + 1 : c;
        half8 wn[8];
        float u0n[8];
#pragma unroll
        for (int z = 0; z < 8; ++z) u0n[z] = 0.f;
        {
            const u16* wc = wb + (size_t)cn * 4096;
#pragma unroll
            for (int tw = 0; tw < 4; ++tw) {
                wn[tw * 2 + 0] = *(const half8*)(wc + (size_t)tw * 1024 + l * 16);
                wn[tw * 2 + 1] = *(const half8*)(wc + (size_t)tw * 1024 + l * 16 + 8);
            }
            if (tb) {
#pragma unroll
                for (int mt = 0; mt < 2; ++mt)
#pragma unroll
                    for (int i = 0; i < 4; ++i)
                        u0n[mt * 4 + i] = ub[(size_t)(cn * 32 + mt * 16 + h * 4 + i) * 64 + n];
            }
        }

        asm volatile("s_waitcnt lgkmcnt(0)" ::: "memory");
        half8 SBhi[2], SBlo[2];
#pragma unroll
        for (int kt = 0; kt < 2; ++kt) {
            f32x4 a = *(const f32x4*)&Sc[n * 76 + kt * 32 + h * 8];
            f32x4 b = *(const f32x4*)&Sc[n * 76 + kt * 32 + h * 8 + 4];
            half8 hi, lo;
#pragma unroll
            for (int j = 0; j < 4; ++j) {
                float x = a[j];
                _Float16 xh = (_Float16)x;
                hi[j] = xh; lo[j] = (_Float16)(x - (float)xh);
            }
#pragma unroll
            for (int j = 0; j < 4; ++j) {
                float x = b[j];
                _Float16 xh = (_Float16)x;
                hi[4 + j] = xh; lo[4 + j] = (_Float16)(x - (float)xh);
            }
            SBhi[kt] = hi; SBlo[kt] = lo;
        }

        // t = u0 + (-w)@state   (w stored negated)
        f32x4 accu[2];
#pragma unroll
        for (int mt = 0; mt < 2; ++mt) {
            f32x4 a;
            a[0] = u0cur[mt * 4 + 0]; a[1] = u0cur[mt * 4 + 1];
            a[2] = u0cur[mt * 4 + 2]; a[3] = u0cur[mt * 4 + 3];
#pragma unroll
            for (int kt = 0; kt < 2; ++kt) {
                const int tw = mt * 2 + kt;
                a = MFMA16(wcur[tw * 2 + 0], SBhi[kt], a);
                a = MFMA16(wcur[tw * 2 + 0], SBlo[kt], a);
                a = MFMA16(wcur[tw * 2 + 1], SBhi[kt], a);
            }
            accu[mt] = a;
        }

#pragma unroll
        for (int mt = 0; mt < 2; ++mt)
            *(f32x4*)&uc[n * 44 + mt * 16 + h * 4] = accu[mt];
        asm volatile("s_waitcnt lgkmcnt(0)" ::: "memory");
        half8 uBhi, uBlo;
        {
            f32x4 a = *(const f32x4*)&uc[n * 44 + h * 8];
            f32x4 b = *(const f32x4*)&uc[n * 44 + h * 8 + 4];
#pragma unroll
            for (int j = 0; j < 4; ++j) {
                float x = a[j];
                _Float16 xh = (_Float16)x;
                uBhi[j] = xh; uBlo[j] = (_Float16)(x - (float)xh);
            }
#pragma unroll
            for (int j = 0; j < 4; ++j) {
                float x = b[j];
                _Float16 xh = (_Float16)x;
                uBhi[4 + j] = xh; uBlo[4 + j] = (_Float16)(x - (float)xh);
            }
        }

        // state += kT @ t
#pragma unroll
        for (int mt = 0; mt < 4; ++mt) {
            f32x4 a = Sacc[mt];
            a = MFMA16(kT[mt * 2 + 0], uBhi, a);
            a = MFMA16(kT[mt * 2 + 0], uBlo, a);
            a = MFMA16(kT[mt * 2 + 1], uBhi, a);
            Sacc[mt] = a;
        }

#pragma unroll
        for (int z = 0; z < 8; ++z) wcur[z] = wn[z];
#pragma unroll
        for (int z = 0; z < 8; ++z) u0cur[z] = u0n[z];
    }

    float* ob = (tb ? Bbuf : Tbuf) + (size_t)bhseg * 4096;
#pragma unroll
    for (int mt = 0; mt < 4; ++mt)
#pragma unroll
        for (int i = 0; i < 4; ++i)
            ob[(size_t)(16 * mt + 4 * h + i) * 64 + g * 16 + n] = Sacc[mt][i];
}

// ---------------------------------------------------------------------------
// Pass 2: compose segment starting states.
//   S_start[0] = 0;  S_start[s+1] = T_s @ S_start[s] + B_s
// 128 blocks (32 bh x 4 col-groups), 1 wave. NSEG sequential steps of
// 64x64 @ 64x16 hi/lo MFMA. Also emits final S -> s_out.
// ---------------------------------------------------------------------------
__global__ __launch_bounds__(64) void compose_kernel(
    const float* __restrict__ Tbuf, const float* __restrict__ Bbuf,
    float* __restrict__ Sst, float* __restrict__ s_out)
{
    const int bh = blockIdx.x & 31;
    const int g = blockIdx.x >> 5;
    const int l = threadIdx.x;
    const int n = l & 15, h = l >> 4;
    __shared__ __align__(16) float Sc[16 * 76];

    f32x4 S[4];
    const f32x4 fzero = {0.f, 0.f, 0.f, 0.f};
#pragma unroll
    for (int mt = 0; mt < 4; ++mt) S[mt] = fzero;

    for (int s = 0; s < NSEG; ++s) {
        const size_t mb = (size_t)(bh * NSEG + s) * 4096;
        // store S_start[s] (pass 3 init; s=0 stores zeros)
#pragma unroll
        for (int mt = 0; mt < 4; ++mt)
#pragma unroll
            for (int i = 0; i < 4; ++i)
                Sst[mb + (size_t)(16 * mt + 4 * h + i) * 64 + g * 16 + n] = S[mt][i];

        // issue global loads early: T rows as A-frag sources + B as acc init
        f32x4 tr[16];
#pragma unroll
        for (int mt = 0; mt < 4; ++mt)
#pragma unroll
            for (int kkt = 0; kkt < 2; ++kkt) {
                tr[mt * 4 + kkt * 2 + 0] =
                    *(const f32x4*)&Tbuf[mb + (size_t)(16 * mt + n) * 64 + 32 * kkt + 8 * h];
                tr[mt * 4 + kkt * 2 + 1] =
                    *(const f32x4*)&Tbuf[mb + (size_t)(16 * mt + n) * 64 + 32 * kkt + 8 * h + 4];
            }
        f32x4 acc[4];
#pragma unroll
        for (int mt = 0; mt < 4; ++mt)
#pragma unroll
            for (int i = 0; i < 4; ++i)
                acc[mt][i] = Bbuf[mb + (size_t)(16 * mt + 4 * h + i) * 64 + g * 16 + n];

        // S C->B via LDS (same transform as scan)
#pragma unroll
        for (int mt = 0; mt < 4; ++mt)
            *(f32x4*)&Sc[n * 76 + mt * 16 + h * 4] = S[mt];
        asm volatile("s_waitcnt lgkmcnt(0)" ::: "memory");
        half8 SBhi[2], SBlo[2];
#pragma unroll
        for (int kt = 0; kt < 2; ++kt) {
            f32x4 a = *(const f32x4*)&Sc[n * 76 + kt * 32 + h * 8];
            f32x4 b = *(const f32x4*)&Sc[n * 76 + kt * 32 + h * 8 + 4];
            half8 hi, lo;
#pragma unroll
            for (int j = 0; j < 4; ++j) {
                float x = a[j];
                _Float16 xh = (_Float16)x;
                hi[j] = xh; lo[j] = (_Float16)(x - (float)xh);
            }
#pragma unroll
            for (int j = 0; j < 4; ++j) {
                float x = b[j];
                _Float16 xh = (_Float16)x;
                hi[4 + j] = xh; lo[4 + j] = (_Float16)(x - (float)xh);
            }
            SBhi[kt] = hi; SBlo[kt] = lo;
        }

        // S_next = T @ S + B  (hi/lo split, drop lo*lo)
#pragma unroll
        for (int mt = 0; mt < 4; ++mt) {
            f32x4 a = acc[mt];
#pragma unroll
            for (int kkt = 0; kkt < 2; ++kkt) {
                float t8[8];
                f32x4 t0 = tr[mt * 4 + kkt * 2 + 0];
                f32x4 t1 = tr[mt * 4 + kkt * 2 + 1];
#pragma unroll
                for (int j = 0; j < 4; ++j) { t8[j] = t0[j]; t8[4 + j] = t1[j]; }
                half8 thi, tlo;
                split8(t8, &thi, &tlo);
                a = MFMA16(thi, SBhi[kkt], a);
                a = MFMA16(thi, SBlo[kkt], a);
                a = MFMA16(tlo, SBhi[kkt], a);
            }
            S[mt] = a;
        }
    }

    // final state -> s_out
#pragma unroll
    for (int mt = 0; mt < 4; ++mt)
#pragma unroll
        for (int i = 0; i < 4; ++i)
            s_out[(size_t)bh * (DD * DD) + (size_t)(16 * mt + 4 * h + i) * 64 + g * 16 + n] =
                S[mt][i];
}

// ---------------------------------------------------------------------------
// Pass 3: per-segment replay with o-phase. Identical math to the old scan,
// but 2048 blocks (32 bh x 16 seg x 4 g) x 16 chunks, init from Sst.
// ---------------------------------------------------------------------------
__global__ __launch_bounds__(64) void seg_scan_kernel(
    const u16* __restrict__ wfrag, const u16* __restrict__ ktfrag,
    const u16* __restrict__ qfrag, const u16* __restrict__ pfrag,
    const float* __restrict__ Sst, float* __restrict__ uo)
{
    const int idx = blockIdx.x;
    const int bhseg = idx & SEGMASK;  // bh*NSEG + seg  (same-XCD for shared frags)
    const int g = idx >> SEGSHIFT;    // 0..3
    const int bh = bhseg >> 4, seg = bhseg & (NSEG - 1);
    const int l = threadIdx.x;
    const int n = l & 15, h = l >> 4;
    const int c0 = seg * CPS, c1 = c0 + CPS;

    __shared__ __align__(16) float Sc[16 * 76];
    __shared__ __align__(16) float uc[16 * 44];

    const u16* wb = wfrag + (size_t)bh * 256 * 4096;
    const u16* kb = ktfrag + (size_t)bh * 256 * 4096;
    const u16* qb = qfrag + (size_t)bh * 256 * 2048;
    const u16* pb = pfrag + (size_t)bh * 256 * 1024;
    float* ub = uo + (size_t)bh * SEQ * DD + (size_t)g * 16;

    const f32x4 fzero = {0.f, 0.f, 0.f, 0.f};
    f32x4 Sacc[4];
    {
        const float* sb = Sst + (size_t)bhseg * 4096;
#pragma unroll
        for (int mt = 0; mt < 4; ++mt)
#pragma unroll
            for (int i = 0; i < 4; ++i)
                Sacc[mt][i] = sb[(size_t)(16 * mt + 4 * h + i) * 64 + g * 16 + n];
    }

    // prefetch chunk c0: w frags + u0
    half8 wcur[8];
    float u0cur[8];
    {
        const u16* wc = wb + (size_t)c0 * 4096;
#pragma unroll
        for (int tw = 0; tw < 4; ++tw) {
            wcur[tw * 2 + 0] = *(const half8*)(wc + (size_t)tw * 1024 + l * 16);
            wcur[tw * 2 + 1] = *(const half8*)(wc + (size_t)tw * 1024 + l * 16 + 8);
        }
#pragma unroll
        for (int mt = 0; mt < 2; ++mt)
#pragma unroll
            for (int i = 0; i < 4; ++i)
                u0cur[mt * 4 + i] = ub[(size_t)(c0 * 32 + mt * 16 + h * 4 + i) * 64 + n];
    }

    for (int c = c0; c < c1; ++c) {
#pragma unroll
        for (int mt = 0; mt < 4; ++mt)
            *(f32x4*)&Sc[n * 76 + mt * 16 + h * 4] = Sacc[mt];

        const u16* kc = kb + (size_t)c * 4096;
        half8 kT[8];
#pragma unroll
        for (int mt = 0; mt < 4; ++mt) {
            kT[mt * 2 + 0] = *(const half8*)(kc + (size_t)mt * 1024 + l * 16);
            kT[mt * 2 + 1] = *(const half8*)(kc + (size_t)mt * 1024 + l * 16 + 8);
        }
        const u16* qc = qb + (size_t)c * 2048;
        half8 qh[4];
#pragma unroll
        for (int tw = 0; tw < 4; ++tw) qh[tw] = *(const half8*)(qc + (size_t)tw * 512 + l * 8);
        const u16* pc = pb + (size_t)c * 1024;
        half8 Ph[2];
#pragma unroll
        for (int mt = 0; mt < 2; ++mt) Ph[mt] = *(const half8*)(pc + (size_t)mt * 512 + l * 8);

        const int cn = (c + 1 < c1) ? c + 1 : c;
        half8 wn[8];
        float u0n[8];
        {
            const u16* wc = wb + (size_t)cn * 4096;
#pragma unroll
            for (int tw = 0; tw < 4; ++tw) {
                wn[tw * 2 + 0] = *(const half8*)(wc + (size_t)tw * 1024 + l * 16);
                wn[tw * 2 + 1] = *(const half8*)(wc + (size_t)tw * 1024 + l * 16 + 8);
            }
#pragma unroll
            for (int mt = 0; mt < 2; ++mt)
#pragma unroll
                for (int i = 0; i < 4; ++i)
                    u0n[mt * 4 + i] = ub[(size_t)(cn * 32 + mt * 16 + h * 4 + i) * 64 + n];
        }

        asm volatile("s_waitcnt lgkmcnt(0)" ::: "memory");
        half8 SBhi[2], SBlo[2];
#pragma unroll
        for (int kt = 0; kt < 2; ++kt) {
            f32x4 a = *(const f32x4*)&Sc[n * 76 + kt * 32 + h * 8];
            f32x4 b = *(const f32x4*)&Sc[n * 76 + kt * 32 + h * 8 + 4];
            half8 hi, lo;
#pragma unroll
            for (int j = 0; j < 4; ++j) {
                float x = a[j];
                _Float16 xh = (_Float16)x;
                hi[j] = xh; lo[j] = (_Float16)(x - (float)xh);
            }
#pragma unroll
            for (int j = 0; j < 4; ++j) {
                float x = b[j];
                _Float16 xh = (_Float16)x;
                hi[4 + j] = xh; lo[4 + j] = (_Float16)(x - (float)xh);
            }
            SBhi[kt] = hi; SBlo[kt] = lo;
        }

        // u = u0 - w@S
        f32x4 accu[2];
#pragma unroll
        for (int mt = 0; mt < 2; ++mt) {
            f32x4 a;
            a[0] = u0cur[mt * 4 + 0]; a[1] = u0cur[mt * 4 + 1];
            a[2] = u0cur[mt * 4 + 2]; a[3] = u0cur[mt * 4 + 3];
#pragma unroll
            for (int kt = 0; kt < 2; ++kt) {
                const int tw = mt * 2 + kt;
                a = MFMA16(wcur[tw * 2 + 0], SBhi[kt], a);
                a = MFMA16(wcur[tw * 2 + 0], SBlo[kt], a);
                a = MFMA16(wcur[tw * 2 + 1], SBhi[kt], a);
            }
            accu[mt] = a;
        }

#pragma unroll
        for (int mt = 0; mt < 2; ++mt)
            *(f32x4*)&uc[n * 44 + mt * 16 + h * 4] = accu[mt];
        asm volatile("s_waitcnt lgkmcnt(0)" ::: "memory");
        half8 uBhi, uBlo;
        {
            f32x4 a = *(const f32x4*)&uc[n * 44 + h * 8];
            f32x4 b = *(const f32x4*)&uc[n * 44 + h * 8 + 4];
#pragma unroll
            for (int j = 0; j < 4; ++j) {
                float x = a[j];
                _Float16 xh = (_Float16)x;
                uBhi[j] = xh; uBlo[j] = (_Float16)(x - (float)xh);
            }
#pragma unroll
            for (int j = 0; j < 4; ++j) {
                float x = b[j];
                _Float16 xh = (_Float16)x;
                uBhi[4 + j] = xh; uBlo[4 + j] = (_Float16)(x - (float)xh);
            }
        }

        // S += kT @ u
#pragma unroll
        for (int mt = 0; mt < 4; ++mt) {
            f32x4 a = Sacc[mt];
            a = MFMA16(kT[mt * 2 + 0], uBhi, a);
            a = MFMA16(kT[mt * 2 + 0], uBlo, a);
            a = MFMA16(kT[mt * 2 + 1], uBhi, a);
            Sacc[mt] = a;
        }

        // o = q@S + P@u ; store over u0 slice
#pragma unroll
        for (int mt = 0; mt < 2; ++mt) {
            f32x4 o = fzero;
#pragma unroll
            for (int kt = 0; kt < 2; ++kt) {
                o = MFMA16(qh[mt * 2 + kt], SBhi[kt], o);
                o = MFMA16(qh[mt * 2 + kt], SBlo[kt], o);
            }
            o = MFMA16(Ph[mt], uBhi, o);
            o = MFMA16(Ph[mt], uBlo, o);
#pragma unroll
            for (int i = 0; i < 4; ++i)
                ub[(size_t)(c * 32 + mt * 16 + h * 4 + i) * 64 + n] = o[i];
        }

#pragma unroll
        for (int z = 0; z < 8; ++z) wcur[z] = wn[z];
#pragma unroll
        for (int z = 0; z < 8; ++z) u0cur[z] = u0n[z];
    }
    // final S is written by compose_kernel; nothing to do here.
}

extern "C" void kernel_launch(void* const* d_in, const int* in_sizes, int n_in,
                              void* d_out, int out_size, void* d_ws, size_t ws_size,
                              hipStream_t stream) {
    float* q = (float*)d_in[0];
    float* k = (float*)d_in[1];
    float* v = (float*)d_in[2];  // dead after prep -> reused as T/B/Sst scratch
    const float* beta = (const float*)d_in[3];
    float* out = (float*)d_out;
    float* o_region = out;                          // u0 staging then o (64MB)
    float* s_region = out + (size_t)BH * SEQ * DD;  // final S
    u16* qfr = (u16*)d_ws;                          // 32MB q-hi frags
    u16* pfr = (u16*)((char*)d_ws + 33554432);      // 16MB P-hi frags
    const size_t segfloats = (size_t)BH * NSEG * 4096;  // 2M floats = 8MB
    float* Tbuf = v;                                // T matrices
    float* Bbuf = v + segfloats;                    // B matrices
    float* Sst = v + 2 * segfloats;                 // segment start states

    prep_kernel<<<BH * NCHUNK, 256, 0, stream>>>(q, k, v, beta, o_region, qfr, pfr);
    seg_tf_kernel<<<8 * BH * NSEG, 64, 0, stream>>>((const u16*)q, (const u16*)k,
                                                    o_region, Tbuf, Bbuf);
    compose_kernel<<<128, 64, 0, stream>>>(Tbuf, Bbuf, Sst, s_region);
    seg_scan_kernel<<<4 * BH * NSEG, 64, 0, stream>>>((const u16*)q, (const u16*)k,
                                                      qfr, pfr, Sst, o_region);
}

// Round 4
// 441.327 us; speedup vs baseline: 1.1936x; 1.1936x over previous
//
#include <hip/hip_runtime.h>

#define CH 32      // chunk length
#define DD 64      // dk = dv
#define NCHUNK 256 // chunks per (b,h)
#define SEQ 8192   // sequence length
#define BH 32      // b*h
#define NSEG 16    // segments for the two-level scan
#define CPS 16     // chunks per segment (NCHUNK / NSEG)

typedef _Float16 half8 __attribute__((ext_vector_type(8)));
typedef float f32x4 __attribute__((ext_vector_type(4)));
typedef unsigned short u16;

#define MFMA16(a, b, c) __builtin_amdgcn_mfma_f32_16x16x32_f16((a), (b), (c), 0, 0, 0)

// split fp32 -> f16 hi + f16 lo (hi+lo reconstructs to ~2^-21 rel), store frag
__device__ __forceinline__ void split_store(const float* src8, bool neg, u16* dst) {
    half8 hi, lo;
#pragma unroll
    for (int j = 0; j < 8; ++j) {
        float x = neg ? -src8[j] : src8[j];
        _Float16 xh = (_Float16)x;
        hi[j] = xh;
        lo[j] = (_Float16)(x - (float)xh);
    }
    *(half8*)dst = hi;
    *(half8*)(dst + 8) = lo;
}

__device__ __forceinline__ void hi_store(const float* src8, u16* dst) {
    half8 hi;
#pragma unroll
    for (int j = 0; j < 8; ++j) hi[j] = (_Float16)src8[j];
    *(half8*)dst = hi;
}

__device__ __forceinline__ void split8(const float* src8, half8* hi, half8* lo) {
#pragma unroll
    for (int j = 0; j < 8; ++j) {
        float x = src8[j];
        _Float16 xh = (_Float16)x;
        (*hi)[j] = xh;
        (*lo)[j] = (_Float16)(x - (float)xh);
    }
}

// fp32x8 (two f32x4) -> f16 hi/lo split for B-frags
__device__ __forceinline__ void splitB(const f32x4& a, const f32x4& b, half8* hi, half8* lo) {
#pragma unroll
    for (int j = 0; j < 4; ++j) {
        float x = a[j];
        _Float16 xh = (_Float16)x;
        (*hi)[j] = xh; (*lo)[j] = (_Float16)(x - (float)xh);
    }
#pragma unroll
    for (int j = 0; j < 4; ++j) {
        float x = b[j];
        _Float16 xh = (_Float16)x;
        (*hi)[4 + j] = xh; (*lo)[4 + j] = (_Float16)(x - (float)xh);
    }
}

// ---------------------------------------------------------------------------
// Kernel 1: per-chunk preprocessing. One block (256 thr = 4 waves) per chunk.
// Unchanged from the 575us version.
// ---------------------------------------------------------------------------
__global__ __launch_bounds__(256) void prep_kernel(
    float* __restrict__ q, float* __restrict__ k,
    const float* __restrict__ v, const float* __restrict__ beta,
    float* __restrict__ u_out, u16* __restrict__ qfrag, u16* __restrict__ pfrag)
{
    const int blk = blockIdx.x;
    const int bh = blk >> 8;
    const int cc = blk & 255;
    const size_t base = ((size_t)bh * SEQ + (size_t)cc * CH) * DD;
    const int t = threadIdx.x;

    __shared__ __align__(16) float qs[CH][68];
    __shared__ __align__(16) float ks[CH][68];
    __shared__ __align__(16) float kb[CH][68];
    __shared__ __align__(16) float vb[CH][68];
    __shared__ __align__(16) float wl[CH][68];
    __shared__ float A[CH][33];
    __shared__ __align__(16) float Pl[CH][36];
    __shared__ float bet[CH];
    __shared__ float rnq[CH];
    __shared__ float rnk[CH];

    if (t < CH) bet[t] = beta[(size_t)bh * SEQ + (size_t)cc * CH + t];
    for (int rep = 0; rep < 2; ++rep) {
        int idx = t + rep * 256;          // float4 index (512 total per array)
        int r = idx >> 4, d4 = idx & 15;
        float4 vq = *(const float4*)&q[base + (size_t)idx * 4];
        float4 vk = *(const float4*)&k[base + (size_t)idx * 4];
        float4 vv = *(const float4*)&v[base + (size_t)idx * 4];
        *(float4*)&qs[r][4 * d4] = vq;
        *(float4*)&ks[r][4 * d4] = vk;
        *(float4*)&vb[r][4 * d4] = vv;
    }
    __syncthreads();
    if (t < CH) {
        float ss = 0.f;
        for (int d4 = 0; d4 < 16; ++d4) {
            float4 x = *(const float4*)&qs[t][4 * d4];
            ss += x.x * x.x + x.y * x.y + x.z * x.z + x.w * x.w;
        }
        rnq[t] = rsqrtf(ss + 1e-6f);
    } else if (t < 2 * CH) {
        int r = t - CH;
        float ss = 0.f;
        for (int d4 = 0; d4 < 16; ++d4) {
            float4 x = *(const float4*)&ks[r][4 * d4];
            ss += x.x * x.x + x.y * x.y + x.z * x.z + x.w * x.w;
        }
        rnk[r] = rsqrtf(ss + 1e-6f);
    }
    __syncthreads();
    for (int rep = 0; rep < 2; ++rep) {
        int idx = t + rep * 256;
        int r = idx >> 4, d4 = idx & 15;
        float4 vq = *(const float4*)&qs[r][4 * d4];
        float4 vk = *(const float4*)&ks[r][4 * d4];
        float4 vv = *(const float4*)&vb[r][4 * d4];
        float fq = rnq[r], fk = rnk[r], fb = bet[r];
        vq.x *= fq; vq.y *= fq; vq.z *= fq; vq.w *= fq;
        vk.x *= fk; vk.y *= fk; vk.z *= fk; vk.w *= fk;
        float4 vkb = make_float4(vk.x * fb, vk.y * fb, vk.z * fb, vk.w * fb);
        float4 vvb = make_float4(vv.x * fb, vv.y * fb, vv.z * fb, vv.w * fb);
        *(float4*)&qs[r][4 * d4] = vq;
        *(float4*)&ks[r][4 * d4] = vk;
        *(float4*)&kb[r][4 * d4] = vkb;
        *(float4*)&vb[r][4 * d4] = vvb;
    }
    __syncthreads();
    // ---- A/P via MFMA f16 hi/lo ----
    {
        const int l = t & 63, n = l & 15, h = l >> 4;
        const int wv = t >> 6, mt = wv >> 1, nt = wv & 1;
        half8 kbhi[2], kblo[2], qhi[2], qlo[2], khi[2], klo[2];
#pragma unroll
        for (int kt = 0; kt < 2; ++kt) {
            float a8[8], q8[8], b8[8];
#pragma unroll
            for (int jj = 0; jj < 8; ++jj) {
                a8[jj] = kb[16 * mt + n][32 * kt + 8 * h + jj];
                q8[jj] = qs[16 * mt + n][32 * kt + 8 * h + jj];
                b8[jj] = ks[16 * nt + n][32 * kt + 8 * h + jj];
            }
            split8(a8, &kbhi[kt], &kblo[kt]);
            split8(q8, &qhi[kt], &qlo[kt]);
            split8(b8, &khi[kt], &klo[kt]);
        }
        f32x4 gacc = {0.f, 0.f, 0.f, 0.f};
        f32x4 pacc = {0.f, 0.f, 0.f, 0.f};
#pragma unroll
        for (int kt = 0; kt < 2; ++kt) {
            gacc = MFMA16(kbhi[kt], khi[kt], gacc);
            gacc = MFMA16(kbhi[kt], klo[kt], gacc);
            gacc = MFMA16(kblo[kt], khi[kt], gacc);
            pacc = MFMA16(qhi[kt], khi[kt], pacc);
            pacc = MFMA16(qhi[kt], klo[kt], pacc);
            pacc = MFMA16(qlo[kt], khi[kt], pacc);
        }
#pragma unroll
        for (int i = 0; i < 4; ++i) {
            int ig = 16 * mt + 4 * h + i, jg = 16 * nt + n;
            A[ig][jg] = (jg < ig) ? -gacc[i] : 0.f;
            Pl[ig][jg] = (jg <= ig) ? pacc[i] : 0.f;
        }
    }
    __syncthreads();
    // forward substitution, single wave, columns in registers, no barriers.
    if (t < 64) {
        const int col = t & 31;
        float creg[CH];
        #pragma unroll
        for (int j = 0; j < CH; ++j) creg[j] = A[j][col];
        #pragma unroll
        for (int i = 1; i < CH; ++i) {
            float s = 0.f;
            #pragma unroll
            for (int j = 1; j < i; ++j) s += A[i][j] * creg[j];
            if (col < i) creg[i] += s;
        }
        if (t < 32) {
            #pragma unroll
            for (int j = 0; j < CH; ++j) A[j][col] = creg[j];
        }
    }
    __syncthreads();
    // u = (A+I)@vb -> global row-major (o-region) ; w = (A+I)@kb -> wl (LDS)
    if (t < 128) {
        const int d4 = t & 15;
        const int i0 = (t >> 4) * 4;
        float4 su[4], sw[4];
        #pragma unroll
        for (int ii = 0; ii < 4; ++ii) {
            su[ii] = *(const float4*)&vb[i0 + ii][4 * d4];
            sw[ii] = *(const float4*)&kb[i0 + ii][4 * d4];
        }
        for (int j = 0; j <= i0 + 2; ++j) {
            float4 vv = *(const float4*)&vb[j][4 * d4];
            float4 vk = *(const float4*)&kb[j][4 * d4];
            #pragma unroll
            for (int ii = 0; ii < 4; ++ii) {
                float a = (j < i0 + ii) ? A[i0 + ii][j] : 0.f;
                su[ii].x += a * vv.x; su[ii].y += a * vv.y;
                su[ii].z += a * vv.z; su[ii].w += a * vv.w;
                sw[ii].x += a * vk.x; sw[ii].y += a * vk.y;
                sw[ii].z += a * vk.z; sw[ii].w += a * vk.w;
            }
        }
        #pragma unroll
        for (int ii = 0; ii < 4; ++ii) {
            *(float4*)&u_out[base + (size_t)(i0 + ii) * DD + 4 * d4] = su[ii];
            *(float4*)&wl[i0 + ii][4 * d4] = sw[ii];
        }
    }
    __syncthreads();
    // ---- pack phase: f16 frag stores ----
    {
        const int l = t & 63;
        const int n = l & 15, h = l >> 4;
        const int tw = t >> 6;           // 0..3
        const int mt = tw >> 1, kt = tw & 1;
        const size_t cslot = (size_t)bh * 256 + cc;
        // -w hi/lo A-frags -> over q
        {
            float tmp[8];
            #pragma unroll
            for (int j = 0; j < 8; ++j) tmp[j] = wl[mt * 16 + n][kt * 32 + h * 8 + j];
            split_store(tmp, true, (u16*)q + cslot * 4096 + (size_t)tw * 1024 + l * 16);
        }
        // k^T hi/lo A-frags -> over k
        {
            float tmp[8];
            #pragma unroll
            for (int j = 0; j < 8; ++j) tmp[j] = ks[h * 8 + j][tw * 16 + n];
            split_store(tmp, false, (u16*)k + cslot * 4096 + (size_t)tw * 1024 + l * 16);
        }
        // q hi A-frags -> ws
        {
            float tmp[8];
            #pragma unroll
            for (int j = 0; j < 8; ++j) tmp[j] = qs[mt * 16 + n][kt * 32 + h * 8 + j];
            hi_store(tmp, qfrag + cslot * 2048 + (size_t)tw * 512 + l * 8);
        }
        // P hi A-frags -> ws (2 tiles)
        if (t < 128) {
            float tmp[8];
            #pragma unroll
            for (int j = 0; j < 8; ++j) tmp[j] = Pl[tw * 16 + n][h * 8 + j];
            hi_store(tmp, pfrag + cslot * 1024 + (size_t)tw * 512 + l * 8);
        }
    }
}

// ---------------------------------------------------------------------------
// Pass 1: per-segment transfer function.  S' = M S + b, M = I - kT w,
// b = kT u0.  ONE block (8 waves, 512 thr) per (bh,seg): waves 0-3 compute
// the 4 column-groups of T (identity init, no u0), waves 4-7 the 4 groups
// of B (zero init, real u0).  All 8 waves issue IDENTICAL w/kT frag loads
// -> one HBM fetch + 7 L1/L2 hits (read amplification 8 -> ~1; this was
// the scan-side HBM wall measured in R3).  Per-iteration __syncthreads
// only keeps waves time-aligned so duplicate loads stay cache-hot.
// ---------------------------------------------------------------------------
__global__ __launch_bounds__(512) void seg_tf_kernel(
    const u16* __restrict__ wfrag, const u16* __restrict__ ktfrag,
    const float* __restrict__ uo, float* __restrict__ Tbuf, float* __restrict__ Bbuf)
{
    const int bhseg = blockIdx.x;     // bh*NSEG + seg
    const int bh = bhseg >> 4, seg = bhseg & (NSEG - 1);
    const int wv = threadIdx.x >> 6;  // 0..7
    const int g = wv & 3;             // column group (16 cols of state)
    const int tb = wv >> 2;           // 0 = T path, 1 = B path
    const int l = threadIdx.x & 63;
    const int n = l & 15, h = l >> 4;
    const int c0 = seg * CPS, c1 = c0 + CPS;

    __shared__ __align__(16) float Sc[8][16 * 76];
    __shared__ __align__(16) float uc[8][16 * 44];

    const u16* wb = wfrag + (size_t)bh * 256 * 4096;
    const u16* kb = ktfrag + (size_t)bh * 256 * 4096;
    const float* ub = uo + (size_t)bh * SEQ * DD + (size_t)g * 16;

    f32x4 Sacc[4];
    const f32x4 fzero = {0.f, 0.f, 0.f, 0.f};
#pragma unroll
    for (int mt = 0; mt < 4; ++mt) Sacc[mt] = fzero;
    if (!tb) {  // T starts as identity slice: row == global col (g*16+n)
#pragma unroll
        for (int mt = 0; mt < 4; ++mt)
#pragma unroll
            for (int i = 0; i < 4; ++i)
                if (16 * mt + 4 * h + i == g * 16 + n) Sacc[mt][i] = 1.f;
    }

    // prefetch chunk c0: w frags (+ u0 for B path)
    half8 wcur[8];
    float u0cur[8];
#pragma unroll
    for (int z = 0; z < 8; ++z) u0cur[z] = 0.f;
    {
        const u16* wc = wb + (size_t)c0 * 4096;
#pragma unroll
        for (int tw = 0; tw < 4; ++tw) {
            wcur[tw * 2 + 0] = *(const half8*)(wc + (size_t)tw * 1024 + l * 16);
            wcur[tw * 2 + 1] = *(const half8*)(wc + (size_t)tw * 1024 + l * 16 + 8);
        }
        if (tb) {
#pragma unroll
            for (int mt = 0; mt < 2; ++mt)
#pragma unroll
                for (int i = 0; i < 4; ++i)
                    u0cur[mt * 4 + i] = ub[(size_t)(c0 * 32 + mt * 16 + h * 4 + i) * 64 + n];
        }
    }

    for (int c = c0; c < c1; ++c) {
        __syncthreads();   // time-align waves (cache reuse), no data hazard
#pragma unroll
        for (int mt = 0; mt < 4; ++mt)
            *(f32x4*)&Sc[wv][n * 76 + mt * 16 + h * 4] = Sacc[mt];

        const u16* kc = kb + (size_t)c * 4096;
        half8 kT[8];
#pragma unroll
        for (int mt = 0; mt < 4; ++mt) {
            kT[mt * 2 + 0] = *(const half8*)(kc + (size_t)mt * 1024 + l * 16);
            kT[mt * 2 + 1] = *(const half8*)(kc + (size_t)mt * 1024 + l * 16 + 8);
        }

        const int cn = (c + 1 < c1) ? c + 1 : c;
        half8 wn[8];
        float u0n[8];
#pragma unroll
        for (int z = 0; z < 8; ++z) u0n[z] = 0.f;
        {
            const u16* wc = wb + (size_t)cn * 4096;
#pragma unroll
            for (int tw = 0; tw < 4; ++tw) {
                wn[tw * 2 + 0] = *(const half8*)(wc + (size_t)tw * 1024 + l * 16);
                wn[tw * 2 + 1] = *(const half8*)(wc + (size_t)tw * 1024 + l * 16 + 8);
            }
            if (tb) {
#pragma unroll
                for (int mt = 0; mt < 2; ++mt)
#pragma unroll
                    for (int i = 0; i < 4; ++i)
                        u0n[mt * 4 + i] = ub[(size_t)(cn * 32 + mt * 16 + h * 4 + i) * 64 + n];
            }
        }

        asm volatile("s_waitcnt lgkmcnt(0)" ::: "memory");
        half8 SBhi[2], SBlo[2];
#pragma unroll
        for (int kt = 0; kt < 2; ++kt) {
            f32x4 a = *(const f32x4*)&Sc[wv][n * 76 + kt * 32 + h * 8];
            f32x4 b = *(const f32x4*)&Sc[wv][n * 76 + kt * 32 + h * 8 + 4];
            splitB(a, b, &SBhi[kt], &SBlo[kt]);
        }

        // t = u0 + (-w)@state   (w stored negated)
        f32x4 accu[2];
#pragma unroll
        for (int mt = 0; mt < 2; ++mt) {
            f32x4 a;
            a[0] = u0cur[mt * 4 + 0]; a[1] = u0cur[mt * 4 + 1];
            a[2] = u0cur[mt * 4 + 2]; a[3] = u0cur[mt * 4 + 3];
#pragma unroll
            for (int kt = 0; kt < 2; ++kt) {
                const int tw = mt * 2 + kt;
                a = MFMA16(wcur[tw * 2 + 0], SBhi[kt], a);
                a = MFMA16(wcur[tw * 2 + 0], SBlo[kt], a);
                a = MFMA16(wcur[tw * 2 + 1], SBhi[kt], a);
            }
            accu[mt] = a;
        }

#pragma unroll
        for (int mt = 0; mt < 2; ++mt)
            *(f32x4*)&uc[wv][n * 44 + mt * 16 + h * 4] = accu[mt];
        asm volatile("s_waitcnt lgkmcnt(0)" ::: "memory");
        half8 uBhi, uBlo;
        {
            f32x4 a = *(const f32x4*)&uc[wv][n * 44 + h * 8];
            f32x4 b = *(const f32x4*)&uc[wv][n * 44 + h * 8 + 4];
            splitB(a, b, &uBhi, &uBlo);
        }

        // state += kT @ t
#pragma unroll
        for (int mt = 0; mt < 4; ++mt) {
            f32x4 a = Sacc[mt];
            a = MFMA16(kT[mt * 2 + 0], uBhi, a);
            a = MFMA16(kT[mt * 2 + 0], uBlo, a);
            a = MFMA16(kT[mt * 2 + 1], uBhi, a);
            Sacc[mt] = a;
        }

#pragma unroll
        for (int z = 0; z < 8; ++z) wcur[z] = wn[z];
#pragma unroll
        for (int z = 0; z < 8; ++z) u0cur[z] = u0n[z];
    }

    float* ob = (tb ? Bbuf : Tbuf) + (size_t)bhseg * 4096;
#pragma unroll
    for (int mt = 0; mt < 4; ++mt)
#pragma unroll
        for (int i = 0; i < 4; ++i)
            ob[(size_t)(16 * mt + 4 * h + i) * 64 + g * 16 + n] = Sacc[mt][i];
}

// ---------------------------------------------------------------------------
// Pass 2: compose segment starting states.
//   S_start[0] = 0;  S_start[s+1] = T_s @ S_start[s] + B_s
// 128 blocks (32 bh x 4 col-groups), 1 wave. NSEG sequential steps of
// 64x64 @ 64x16 hi/lo MFMA. Also emits final S -> s_out.
// ---------------------------------------------------------------------------
__global__ __launch_bounds__(64) void compose_kernel(
    const float* __restrict__ Tbuf, const float* __restrict__ Bbuf,
    float* __restrict__ Sst, float* __restrict__ s_out)
{
    const int bh = blockIdx.x & 31;
    const int g = blockIdx.x >> 5;
    const int l = threadIdx.x;
    const int n = l & 15, h = l >> 4;
    __shared__ __align__(16) float Sc[16 * 76];

    f32x4 S[4];
    const f32x4 fzero = {0.f, 0.f, 0.f, 0.f};
#pragma unroll
    for (int mt = 0; mt < 4; ++mt) S[mt] = fzero;

    for (int s = 0; s < NSEG; ++s) {
        const size_t mb = (size_t)(bh * NSEG + s) * 4096;
        // store S_start[s] (pass 3 init; s=0 stores zeros)
#pragma unroll
        for (int mt = 0; mt < 4; ++mt)
#pragma unroll
            for (int i = 0; i < 4; ++i)
                Sst[mb + (size_t)(16 * mt + 4 * h + i) * 64 + g * 16 + n] = S[mt][i];

        // issue global loads early: T rows as A-frag sources + B as acc init
        f32x4 tr[16];
#pragma unroll
        for (int mt = 0; mt < 4; ++mt)
#pragma unroll
            for (int kkt = 0; kkt < 2; ++kkt) {
                tr[mt * 4 + kkt * 2 + 0] =
                    *(const f32x4*)&Tbuf[mb + (size_t)(16 * mt + n) * 64 + 32 * kkt + 8 * h];
                tr[mt * 4 + kkt * 2 + 1] =
                    *(const f32x4*)&Tbuf[mb + (size_t)(16 * mt + n) * 64 + 32 * kkt + 8 * h + 4];
            }
        f32x4 acc[4];
#pragma unroll
        for (int mt = 0; mt < 4; ++mt)
#pragma unroll
            for (int i = 0; i < 4; ++i)
                acc[mt][i] = Bbuf[mb + (size_t)(16 * mt + 4 * h + i) * 64 + g * 16 + n];

        // S C->B via LDS (same transform as scan)
#pragma unroll
        for (int mt = 0; mt < 4; ++mt)
            *(f32x4*)&Sc[n * 76 + mt * 16 + h * 4] = S[mt];
        asm volatile("s_waitcnt lgkmcnt(0)" ::: "memory");
        half8 SBhi[2], SBlo[2];
#pragma unroll
        for (int kt = 0; kt < 2; ++kt) {
            f32x4 a = *(const f32x4*)&Sc[n * 76 + kt * 32 + h * 8];
            f32x4 b = *(const f32x4*)&Sc[n * 76 + kt * 32 + h * 8 + 4];
            splitB(a, b, &SBhi[kt], &SBlo[kt]);
        }

        // S_next = T @ S + B  (hi/lo split, drop lo*lo)
#pragma unroll
        for (int mt = 0; mt < 4; ++mt) {
            f32x4 a = acc[mt];
#pragma unroll
            for (int kkt = 0; kkt < 2; ++kkt) {
                float t8[8];
                f32x4 t0 = tr[mt * 4 + kkt * 2 + 0];
                f32x4 t1 = tr[mt * 4 + kkt * 2 + 1];
#pragma unroll
                for (int j = 0; j < 4; ++j) { t8[j] = t0[j]; t8[4 + j] = t1[j]; }
                half8 thi, tlo;
                split8(t8, &thi, &tlo);
                a = MFMA16(thi, SBhi[kkt], a);
                a = MFMA16(thi, SBlo[kkt], a);
                a = MFMA16(tlo, SBhi[kkt], a);
            }
            S[mt] = a;
        }
    }

    // final state -> s_out
#pragma unroll
    for (int mt = 0; mt < 4; ++mt)
#pragma unroll
        for (int i = 0; i < 4; ++i)
            s_out[(size_t)bh * (DD * DD) + (size_t)(16 * mt + 4 * h + i) * 64 + g * 16 + n] =
                S[mt][i];
}

// ---------------------------------------------------------------------------
// Pass 3: per-segment replay with o-phase.  ONE block (4 waves, 256 thr)
// per (bh,seg): wave wv handles column group g=wv.  All 4 waves issue the
// same w/kT/q/P frag loads -> L1/L2 hits (amplification 4 -> ~1).
// ---------------------------------------------------------------------------
__global__ __launch_bounds__(256) void seg_scan_kernel(
    const u16* __restrict__ wfrag, const u16* __restrict__ ktfrag,
    const u16* __restrict__ qfrag, const u16* __restrict__ pfrag,
    const float* __restrict__ Sst, float* __restrict__ uo)
{
    const int bhseg = blockIdx.x;     // bh*NSEG + seg
    const int bh = bhseg >> 4, seg = bhseg & (NSEG - 1);
    const int wv = threadIdx.x >> 6;  // 0..3 = column group
    const int g = wv;
    const int l = threadIdx.x & 63;
    const int n = l & 15, h = l >> 4;
    const int c0 = seg * CPS, c1 = c0 + CPS;

    __shared__ __align__(16) float Sc[4][16 * 76];
    __shared__ __align__(16) float uc[4][16 * 44];

    const u16* wb = wfrag + (size_t)bh * 256 * 4096;
    const u16* kb = ktfrag + (size_t)bh * 256 * 4096;
    const u16* qb = qfrag + (size_t)bh * 256 * 2048;
    const u16* pb = pfrag + (size_t)bh * 256 * 1024;
    float* ub = uo + (size_t)bh * SEQ * DD + (size_t)g * 16;

    const f32x4 fzero = {0.f, 0.f, 0.f, 0.f};
    f32x4 Sacc[4];
    {
        const float* sb = Sst + (size_t)bhseg * 4096;
#pragma unroll
        for (int mt = 0; mt < 4; ++mt)
#pragma unroll
            for (int i = 0; i < 4; ++i)
                Sacc[mt][i] = sb[(size_t)(16 * mt + 4 * h + i) * 64 + g * 16 + n];
    }

    // prefetch chunk c0: w frags + u0
    half8 wcur[8];
    float u0cur[8];
    {
        const u16* wc = wb + (size_t)c0 * 4096;
#pragma unroll
        for (int tw = 0; tw < 4; ++tw) {
            wcur[tw * 2 + 0] = *(const half8*)(wc + (size_t)tw * 1024 + l * 16);
            wcur[tw * 2 + 1] = *(const half8*)(wc + (size_t)tw * 1024 + l * 16 + 8);
        }
#pragma unroll
        for (int mt = 0; mt < 2; ++mt)
#pragma unroll
            for (int i = 0; i < 4; ++i)
                u0cur[mt * 4 + i] = ub[(size_t)(c0 * 32 + mt * 16 + h * 4 + i) * 64 + n];
    }

    for (int c = c0; c < c1; ++c) {
        __syncthreads();   // time-align waves (cache reuse), no data hazard
#pragma unroll
        for (int mt = 0; mt < 4; ++mt)
            *(f32x4*)&Sc[wv][n * 76 + mt * 16 + h * 4] = Sacc[mt];

        const u16* kc = kb + (size_t)c * 4096;
        half8 kT[8];
#pragma unroll
        for (int mt = 0; mt < 4; ++mt) {
            kT[mt * 2 + 0] = *(const half8*)(kc + (size_t)mt * 1024 + l * 16);
            kT[mt * 2 + 1] = *(const half8*)(kc + (size_t)mt * 1024 + l * 16 + 8);
        }
        const u16* qc = qb + (size_t)c * 2048;
        half8 qh[4];
#pragma unroll
        for (int tw = 0; tw < 4; ++tw) qh[tw] = *(const half8*)(qc + (size_t)tw * 512 + l * 8);
        const u16* pc = pb + (size_t)c * 1024;
        half8 Ph[2];
#pragma unroll
        for (int mt = 0; mt < 2; ++mt) Ph[mt] = *(const half8*)(pc + (size_t)mt * 512 + l * 8);

        const int cn = (c + 1 < c1) ? c + 1 : c;
        half8 wn[8];
        float u0n[8];
        {
            const u16* wc = wb + (size_t)cn * 4096;
#pragma unroll
            for (int tw = 0; tw < 4; ++tw) {
                wn[tw * 2 + 0] = *(const half8*)(wc + (size_t)tw * 1024 + l * 16);
                wn[tw * 2 + 1] = *(const half8*)(wc + (size_t)tw * 1024 + l * 16 + 8);
            }
#pragma unroll
            for (int mt = 0; mt < 2; ++mt)
#pragma unroll
                for (int i = 0; i < 4; ++i)
                    u0n[mt * 4 + i] = ub[(size_t)(cn * 32 + mt * 16 + h * 4 + i) * 64 + n];
        }

        asm volatile("s_waitcnt lgkmcnt(0)" ::: "memory");
        half8 SBhi[2], SBlo[2];
#pragma unroll
        for (int kt = 0; kt < 2; ++kt) {
            f32x4 a = *(const f32x4*)&Sc[wv][n * 76 + kt * 32 + h * 8];
            f32x4 b = *(const f32x4*)&Sc[wv][n * 76 + kt * 32 + h * 8 + 4];
            splitB(a, b, &SBhi[kt], &SBlo[kt]);
        }

        // u = u0 - w@S
        f32x4 accu[2];
#pragma unroll
        for (int mt = 0; mt < 2; ++mt) {
            f32x4 a;
            a[0] = u0cur[mt * 4 + 0]; a[1] = u0cur[mt * 4 + 1];
            a[2] = u0cur[mt * 4 + 2]; a[3] = u0cur[mt * 4 + 3];
#pragma unroll
            for (int kt = 0; kt < 2; ++kt) {
                const int tw = mt * 2 + kt;
                a = MFMA16(wcur[tw * 2 + 0], SBhi[kt], a);
                a = MFMA16(wcur[tw * 2 + 0], SBlo[kt], a);
                a = MFMA16(wcur[tw * 2 + 1], SBhi[kt], a);
            }
            accu[mt] = a;
        }

#pragma unroll
        for (int mt = 0; mt < 2; ++mt)
            *(f32x4*)&uc[wv][n * 44 + mt * 16 + h * 4] = accu[mt];
        asm volatile("s_waitcnt lgkmcnt(0)" ::: "memory");
        half8 uBhi, uBlo;
        {
            f32x4 a = *(const f32x4*)&uc[wv][n * 44 + h * 8];
            f32x4 b = *(const f32x4*)&uc[wv][n * 44 + h * 8 + 4];
            splitB(a, b, &uBhi, &uBlo);
        }

        // S += kT @ u
#pragma unroll
        for (int mt = 0; mt < 4; ++mt) {
            f32x4 a = Sacc[mt];
            a = MFMA16(kT[mt * 2 + 0], uBhi, a);
            a = MFMA16(kT[mt * 2 + 0], uBlo, a);
            a = MFMA16(kT[mt * 2 + 1], uBhi, a);
            Sacc[mt] = a;
        }

        // o = q@S + P@u ; store over u0 slice
#pragma unroll
        for (int mt = 0; mt < 2; ++mt) {
            f32x4 o = fzero;
#pragma unroll
            for (int kt = 0; kt < 2; ++kt) {
                o = MFMA16(qh[mt * 2 + kt], SBhi[kt], o);
                o = MFMA16(qh[mt * 2 + kt], SBlo[kt], o);
            }
            o = MFMA16(Ph[mt], uBhi, o);
            o = MFMA16(Ph[mt], uBlo, o);
#pragma unroll
            for (int i = 0; i < 4; ++i)
                ub[(size_t)(c * 32 + mt * 16 + h * 4 + i) * 64 + n] = o[i];
        }

#pragma unroll
        for (int z = 0; z < 8; ++z) wcur[z] = wn[z];
#pragma unroll
        for (int z = 0; z < 8; ++z) u0cur[z] = u0n[z];
    }
    // final S is written by compose_kernel; nothing to do here.
}

extern "C" void kernel_launch(void* const* d_in, const int* in_sizes, int n_in,
                              void* d_out, int out_size, void* d_ws, size_t ws_size,
                              hipStream_t stream) {
    float* q = (float*)d_in[0];
    float* k = (float*)d_in[1];
    float* v = (float*)d_in[2];  // dead after prep -> reused as T/B/Sst scratch
    const float* beta = (const float*)d_in[3];
    float* out = (float*)d_out;
    float* o_region = out;                          // u0 staging then o (64MB)
    float* s_region = out + (size_t)BH * SEQ * DD;  // final S
    u16* qfr = (u16*)d_ws;                          // 32MB q-hi frags
    u16* pfr = (u16*)((char*)d_ws + 33554432);      // 16MB P-hi frags
    const size_t segfloats = (size_t)BH * NSEG * 4096;  // 8MB
    float* Tbuf = v;                                // T matrices
    float* Bbuf = v + segfloats;                    // B matrices
    float* Sst = v + 2 * segfloats;                 // segment start states

    prep_kernel<<<BH * NCHUNK, 256, 0, stream>>>(q, k, v, beta, o_region, qfr, pfr);
    seg_tf_kernel<<<BH * NSEG, 512, 0, stream>>>((const u16*)q, (const u16*)k,
                                                 o_region, Tbuf, Bbuf);
    compose_kernel<<<128, 64, 0, stream>>>(Tbuf, Bbuf, Sst, s_region);
    seg_scan_kernel<<<BH * NSEG, 256, 0, stream>>>((const u16*)q, (const u16*)k,
                                                   qfr, pfr, Sst, o_region);
}